// Round 1
// baseline (360.333 us; speedup 1.0000x reference)
//
#include <hip/hip_runtime.h>
#include <stdint.h>

#define HW        (1024 * 1024)
#define KIDS      64
#define NCANDS    16
#define BCC       76          /* B*C = 4*19 */
#define EPSF      1e-6f
#define MARGINF   1.0f
#define SENTINEL  0x7FFFFFFF

// JAX PRNG variant: 1 = threefry_partitionable (default since JAX 0.5.0),
// 0 = legacy original layout. Flip if absmax mismatch points at the negatives.
#define JAX_PARTITIONABLE 1

__device__ __forceinline__ uint32_t rotl32(uint32_t v, int r) {
    return (v << r) | (v >> (32 - r));
}

// Threefry-2x32, 20 rounds — exact JAX schedule.
__device__ void threefry2x32(uint32_t k0, uint32_t k1, uint32_t x0, uint32_t x1,
                             uint32_t* o0, uint32_t* o1) {
    const uint32_t ks2 = k0 ^ k1 ^ 0x1BD11BDAu;
    const int R0[4] = {13, 15, 26, 6};
    const int R1[4] = {17, 29, 16, 24};
    x0 += k0; x1 += k1;
#pragma unroll
    for (int i = 0; i < 4; i++) { x0 += x1; x1 = rotl32(x1, R0[i]); x1 ^= x0; }
    x0 += k1; x1 += ks2 + 1u;
#pragma unroll
    for (int i = 0; i < 4; i++) { x0 += x1; x1 = rotl32(x1, R1[i]); x1 ^= x0; }
    x0 += ks2; x1 += k0 + 2u;
#pragma unroll
    for (int i = 0; i < 4; i++) { x0 += x1; x1 = rotl32(x1, R0[i]); x1 ^= x0; }
    x0 += k0; x1 += k1 + 3u;
#pragma unroll
    for (int i = 0; i < 4; i++) { x0 += x1; x1 = rotl32(x1, R1[i]); x1 ^= x0; }
    x0 += k1; x1 += ks2 + 4u;
#pragma unroll
    for (int i = 0; i < 4; i++) { x0 += x1; x1 = rotl32(x1, R0[i]); x1 ^= x0; }
    x0 += ks2; x1 += k0 + 5u;
    *o0 = x0; *o1 = x1;
}

// lower_bits[j] for j in [0, 1024): the 32-bit random word whose low 20 bits
// are cand[j/16][j%16]. key(1) -> (0,1); k2 = split(key)[1].
__device__ uint32_t jax_cand_bits(uint32_t j) {
#if JAX_PARTITIONABLE
    uint32_t k2a, k2b;
    threefry2x32(0u, 1u, 0u, 1u, &k2a, &k2b);      // foldlike split: child 1
    uint32_t b1, b2;
    threefry2x32(k2a, k2b, 0u, j, &b1, &b2);       // iota_2x32 counts (0, j)
    return b1 ^ b2;                                // 32-bit path xors halves
#else
    // legacy split: counts iota(4)=[0,1,2,3] -> x0=[0,1], x1=[2,3]
    // k2 = (TF(key,(0,2)).second, TF(key,(1,3)).second)
    uint32_t a0, a1, b0, b1;
    threefry2x32(0u, 1u, 0u, 2u, &a0, &a1);
    threefry2x32(0u, 1u, 1u, 3u, &b0, &b1);
    uint32_t k2a = a1, k2b = b1;
    // random_bits original: counts iota(1024); x0=[0..511], x1=[512..1023]
    uint32_t r0, r1;
    if (j < 512u) { threefry2x32(k2a, k2b, j, j + 512u, &r0, &r1); return r0; }
    else          { threefry2x32(k2a, k2b, j - 512u, j, &r0, &r1); return r1; }
#endif
}

__global__ void k_init(int* g_first, int* g_second, int* g_count,
                       float* g_total, int* g_cnt) {
    int t = threadIdx.x;
    if (t < KIDS) { g_first[t] = SENTINEL; g_second[t] = SENTINEL; g_count[t] = 0; }
    if (t == 0)   { *g_total = 0.0f; *g_cnt = 0; }
}

// One pass over the mask: per-block LDS (min1, min2, count) per id, then merge
// into global. Global second-min uses the displaced-value trick:
//   old = atomicMin(g1, m1); atomicMin(g2, max(old, m1)); atomicMin(g2, m2)
// With linearizable atomics the displaced values across all blocks are exactly
// all block-minima except the global minimum, so g2 ends correct.
__global__ void k_seg(const int* __restrict__ mask,
                      int* g_first, int* g_second, int* g_count) {
    __shared__ int m1[KIDS], m2[KIDS], cnt[KIDS];
    const int t = threadIdx.x;
    if (t < KIDS) { m1[t] = SENTINEL; m2[t] = SENTINEL; cnt[t] = 0; }
    __syncthreads();

    const int4* m4 = (const int4*)mask;
    const int base4 = blockIdx.x * 1024;   // 4096 pixels per block / 4
    int4 v[4];
#pragma unroll
    for (int c = 0; c < 4; c++) v[c] = m4[base4 + c * 256 + t];

#pragma unroll
    for (int c = 0; c < 4; c++) {
        const int pix0 = (base4 + c * 256 + t) * 4;
        const int ids[4] = {v[c].x, v[c].y, v[c].z, v[c].w};
#pragma unroll
        for (int j = 0; j < 4; j++) {
            atomicAdd(&cnt[ids[j]], 1);
            atomicMin(&m1[ids[j]], pix0 + j);
        }
    }
    __syncthreads();
#pragma unroll
    for (int c = 0; c < 4; c++) {
        const int pix0 = (base4 + c * 256 + t) * 4;
        const int ids[4] = {v[c].x, v[c].y, v[c].z, v[c].w};
#pragma unroll
        for (int j = 0; j < 4; j++) {
            if (pix0 + j != m1[ids[j]]) atomicMin(&m2[ids[j]], pix0 + j);
        }
    }
    __syncthreads();

    if (t < KIDS && cnt[t] > 0) {
        const int lm1 = m1[t];
        const int old = atomicMin(&g_first[t], lm1);
        const int disp = old > lm1 ? old : lm1;
        if (disp != SENTINEL)  atomicMin(&g_second[t], disp);
        if (m2[t] != SENTINEL) atomicMin(&g_second[t], m2[t]);
        atomicAdd(&g_count[t], cnt[t]);
    }
}

// One block per instance id: pick the random negative, gather the three
// 76-dim columns, reduce, hinge, accumulate.
__global__ void k_triplet(const float* __restrict__ sem,
                          const int* __restrict__ mask,
                          const int* __restrict__ g_first,
                          const int* __restrict__ g_second,
                          const int* __restrict__ g_count,
                          float* g_total, int* g_cnt) {
    const int k = blockIdx.x;
    if (k == 0 || g_count[k] < 2) return;   // uniform per block

    __shared__ int s_neg;
    __shared__ float red_ap[128], red_an[128];
    const int t = threadIdx.x;

    if (t == 0) {
        int neg = -1, first_cand = -1;
        for (int c = 0; c < NCANDS; c++) {
            const uint32_t bits = jax_cand_bits((uint32_t)(k * NCANDS + c));
            const int cand = (int)(bits & (uint32_t)(HW - 1));
            if (c == 0) first_cand = cand;
            if (neg < 0 && mask[cand] != k) neg = cand;
        }
        s_neg = (neg < 0) ? first_cand : neg;   // argmax(all-False)=0
    }
    __syncthreads();

    const int f = g_first[k], s = g_second[k], n = s_neg;
    float ap = 0.0f, an = 0.0f;
    if (t < BCC) {
        const size_t row = (size_t)t * (size_t)HW;
        const float a  = sem[row + f];
        const float p  = sem[row + s];
        const float nn = sem[row + n];
        const float d1 = a - p + EPSF;
        const float d2 = a - nn + EPSF;
        ap = d1 * d1;
        an = d2 * d2;
    }
    red_ap[t] = ap; red_an[t] = an;
    __syncthreads();
    for (int off = 64; off > 0; off >>= 1) {
        if (t < off) { red_ap[t] += red_ap[t + off]; red_an[t] += red_an[t + off]; }
        __syncthreads();
    }
    if (t == 0) {
        float per = sqrtf(red_ap[0]) - sqrtf(red_an[0]) + MARGINF;
        per = per > 0.0f ? per : 0.0f;
        atomicAdd(g_total, per);
        atomicAdd(g_cnt, 1);
    }
}

__global__ void k_final(const float* __restrict__ g_total,
                        const int* __restrict__ g_cnt, float* out) {
    const int c = *g_cnt;
    out[0] = (c > 0) ? (*g_total / (float)c) : 0.0f;
}

extern "C" void kernel_launch(void* const* d_in, const int* in_sizes, int n_in,
                              void* d_out, int out_size, void* d_ws, size_t ws_size,
                              hipStream_t stream) {
    const float* sem  = (const float*)d_in[0];   // [4,19,1024,1024] f32
    const int*   mask = (const int*)d_in[1];     // [1024,1024] i32
    float* out = (float*)d_out;

    int* ws = (int*)d_ws;
    int* g_first  = ws;             // 64 ints
    int* g_second = ws + 64;        // 64 ints
    int* g_count  = ws + 128;       // 64 ints
    float* g_total = (float*)(ws + 192);
    int*   g_cnt   = ws + 193;

    k_init<<<1, 64, 0, stream>>>(g_first, g_second, g_count, g_total, g_cnt);
    k_seg<<<HW / 4096, 256, 0, stream>>>(mask, g_first, g_second, g_count);
    k_triplet<<<KIDS, 128, 0, stream>>>(sem, mask, g_first, g_second, g_count,
                                        g_total, g_cnt);
    k_final<<<1, 1, 0, stream>>>(g_total, g_cnt, out);
}